// Round 19
// baseline (305.510 us; speedup 1.0000x reference)
//
#include <hip/hip_runtime.h>
#include <hip/hip_bf16.h>
#include <stdint.h>

#define N_NODES 100000
#define E_EDGES 1600000
#define NEG_SLOPE 0.2f
#define NBUCK 1563     // ceil(N/64): bucket = 64 consecutive dst nodes
#define BK_SH 6
#define CAPS 2048      // fixed global evs slots per bucket (mean 1024, ~30 sigma)
#define CAP 1280       // LDS staging cap per bucket in k_aggr (mean+8sigma)
#define CAPP (CAP + 8) // padded leading dim (offsets head rows across banks)
#define OVF_MAX 8192

typedef short short8 __attribute__((ext_vector_type(8)));
typedef float f32x4 __attribute__((ext_vector_type(4)));

__device__ __forceinline__ unsigned short f2bf(float f) {
  union { float f; unsigned int u; } c; c.f = f;
  unsigned int u = c.u;
  unsigned int r = u + 0x7FFFu + ((u >> 16) & 1u);
  return (unsigned short)(r >> 16);
}
__device__ __forceinline__ float asf(unsigned int u) {
  union { unsigned int u; float f; } c; c.u = u;
  return c.f;
}

// ---- detect int32 vs int64 edge_index: int64 => odd int32 words are all 0
__global__ void k_detect(const void* ei, int* flag) {
  int t = threadIdx.x;
  int v = ((const int*)ei)[2 * t + 1];
  unsigned long long b = __ballot(v != 0);
  if (t == 0) *flag = (b != 0ull) ? 1 : 0;  // 1 = int32 layout
}

// ---- pack W -> Bt[col][k] bf16, proj_w -> Pt[col][k] bf16 (identity layout),
//      w3[h][d] = sum_o W_edge[h][d][o]*a3[h][o]
__global__ void k_prep(const float* __restrict__ W, const float* __restrict__ proj_w,
                       const float* __restrict__ W_edge, const float* __restrict__ att,
                       unsigned short* __restrict__ Bt, unsigned short* __restrict__ Pt,
                       float* __restrict__ w3) {
  int t = blockIdx.x * 256 + threadIdx.x;
  if (t < 65536) {
    int col = t >> 8, k = t & 255;
    int h = col >> 6, o = col & 63;
    Bt[t] = f2bf(W[h * 16384 + k * 64 + o]);
  } else if (t < 131072) {
    int t2 = t - 65536;
    int o = t2 >> 8, i = t2 & 255;
    Pt[t2] = f2bf(proj_w[i * 256 + o]);
  } else if (t < 131136) {
    int t3 = t - 131072;
    int h = t3 >> 4, d = t3 & 15;
    float s = 0.f;
    for (int o = 0; o < 64; ++o)
      s += W_edge[h * 1024 + d * 64 + o] * att[h * 192 + 128 + o];
    w3[t3] = s;
  }
}

// ---- GEMM + fused epilogue (scores s1/s2, per-(row,head) BIASED-UNSIGNED int8
//      quant: byte = rn(127*v/mx) + 128) via LDS-transpose epilogue.
//      B-register double-buffered.
__global__ __launch_bounds__(256, 4) void k_gemm_x(const float* __restrict__ x,
    const unsigned short* __restrict__ Bt, const float* __restrict__ att,
    unsigned int* __restrict__ xwq, float* __restrict__ scl4,
    float* __restrict__ s1, float* __restrict__ s2) {
  __shared__ __align__(16) char smem[32768];
  unsigned short* As = (unsigned short*)smem;
  float* Ls = (float*)smem;                    // epilogue transpose, 16x260 fp32
  float* attS = (float*)(smem + 24576);        // 768 floats, above Ls region
  const int bm = blockIdx.x * 64;
  const int t = threadIdx.x;

#pragma unroll
  for (int i = 0; i < 16; ++i) {
    int c = i * 256 + t;
    int row = c >> 6, f4 = c & 63;
    uint2 w = make_uint2(0u, 0u);
    if (bm + row < N_NODES) {
      float4 v = *(const float4*)(x + (size_t)(bm + row) * 256 + f4 * 4);
      w.x = (unsigned int)f2bf(v.x) | ((unsigned int)f2bf(v.y) << 16);
      w.y = (unsigned int)f2bf(v.z) | ((unsigned int)f2bf(v.w) << 16);
    }
    int phys = row * 512 + (((f4 >> 1) ^ (row & 7)) << 4) + ((f4 & 1) << 3);
    *(uint2*)((char*)As + phys) = w;
  }
  __syncthreads();

  const int wave = t >> 6;
  const int lane = t & 63;
  const int l16 = lane & 15, lg = lane >> 4;
  const int colbase = wave * 64;
  f32x4 acc[4][4];
#pragma unroll
  for (int i = 0; i < 4; i++)
#pragma unroll
    for (int j = 0; j < 4; j++) acc[i][j] = (f32x4){0.f, 0.f, 0.f, 0.f};

  short8 bcur[4], bnxt[4];
#pragma unroll
  for (int ni = 0; ni < 4; ni++)
    bcur[ni] = *(const short8*)(Bt + (colbase + ni * 16 + l16) * 256 + lg * 8);

#pragma unroll
  for (int ks = 0; ks < 8; ++ks) {
    short8 a[4];
#pragma unroll
    for (int mi = 0; mi < 4; mi++) {
      int row = mi * 16 + l16;
      int phys = row * 512 + (((ks * 4 + lg) ^ (row & 7)) << 4);
      a[mi] = *(const short8*)((const char*)As + phys);
    }
    if (ks < 7) {
      const int k0n = (ks + 1) * 32 + lg * 8;
#pragma unroll
      for (int ni = 0; ni < 4; ni++)
        bnxt[ni] = *(const short8*)(Bt + (colbase + ni * 16 + l16) * 256 + k0n);
    }
#pragma unroll
    for (int mi = 0; mi < 4; mi++)
#pragma unroll
      for (int ni = 0; ni < 4; ni++)
        acc[mi][ni] = __builtin_amdgcn_mfma_f32_16x16x32_bf16(a[mi], bcur[ni], acc[mi][ni], 0, 0, 0);
#pragma unroll
    for (int ni = 0; ni < 4; ni++) bcur[ni] = bnxt[ni];
  }

  // all waves done reading As before attS (aliased) is written
  __syncthreads();
  for (int i = t; i < 768; i += 256) attS[i] = att[i];

  const int row16 = t >> 4;     // row within 16-row tile
  const int g = t & 15;         // 16-col group; head h = g>>2
  const int h = g >> 2;
  const int cwh = (g & 3) * 16; // col offset within head
#pragma unroll
  for (int mi = 0; mi < 4; mi++) {
    __syncthreads();
#pragma unroll
    for (int r = 0; r < 4; r++)
#pragma unroll
      for (int ni = 0; ni < 4; ni++)
        Ls[(lg * 4 + r) * 260 + colbase + ni * 16 + l16] = acc[mi][ni][r];
    __syncthreads();
    float v[16];
#pragma unroll
    for (int k = 0; k < 4; ++k) {
      float4 f = *(const float4*)&Ls[row16 * 260 + g * 16 + k * 4];
      v[4 * k] = f.x; v[4 * k + 1] = f.y; v[4 * k + 2] = f.z; v[4 * k + 3] = f.w;
    }
    float mx = 0.f, p1 = 0.f, p2 = 0.f;
#pragma unroll
    for (int j = 0; j < 16; ++j) {
      mx = fmaxf(mx, fabsf(v[j]));
      p1 += v[j] * attS[h * 192 + cwh + j];
      p2 += v[j] * attS[h * 192 + 64 + cwh + j];
    }
    mx = fmaxf(mx, __shfl_xor(mx, 1, 64));
    mx = fmaxf(mx, __shfl_xor(mx, 2, 64));
    p1 += __shfl_xor(p1, 1, 64); p1 += __shfl_xor(p1, 2, 64);
    p2 += __shfl_xor(p2, 1, 64); p2 += __shfl_xor(p2, 2, 64);
    int row = bm + mi * 16 + row16;
    if (row < N_NODES) {
      mx += 1e-30f;
      float inv = 127.f / mx;
      uint4 pk;
      unsigned int* pw = &pk.x;
#pragma unroll
      for (int k = 0; k < 4; ++k) {
        unsigned int q0 = (unsigned int)(__float2int_rn(v[4 * k] * inv) + 128);
        unsigned int q1 = (unsigned int)(__float2int_rn(v[4 * k + 1] * inv) + 128);
        unsigned int q2 = (unsigned int)(__float2int_rn(v[4 * k + 2] * inv) + 128);
        unsigned int q3 = (unsigned int)(__float2int_rn(v[4 * k + 3] * inv) + 128);
        pw[k] = q0 | (q1 << 8) | (q2 << 16) | (q3 << 24);
      }
      *(uint4*)(xwq + (size_t)row * 64 + g * 4) = pk;
      if ((g & 3) == 0) {
        scl4[row * 4 + h] = mx * (1.f / 127.f);
        s1[row * 4 + h] = p1;
        s2[row * 4 + h] = p2;
      }
    }
  }
}

// ---- per-edge compute + bucket-partitioned scatter into FIXED 2048-slot bucket
//      regions. Block-private runs via one atomicAdd(bcur[bk], c); overflow
//      spills to global ovf list.
__global__ __launch_bounds__(1024) void k_edge(const void* ei, const int* __restrict__ flag,
                       const float* __restrict__ edge_attr,
                       const float* __restrict__ s1, const float* __restrict__ s2,
                       const float* __restrict__ w3g, int* __restrict__ bcur,
                       uint4* __restrict__ evs, uint4* __restrict__ ovf,
                       int* __restrict__ ovfc) {
  __shared__ float w3[64];
  __shared__ int cnt[NBUCK];
  __shared__ int rb[NBUCK];
  __shared__ int cur[NBUCK];
  const int t = threadIdx.x;
  for (int i = t; i < NBUCK; i += 1024) { cnt[i] = 0; cur[i] = 0; }
  if (t < 64) w3[t] = w3g[t];
  __syncthreads();

  const int f = *flag;
  const int base = blockIdx.x * 4096;
  int dstv[4], srcv[4];
  unsigned int pav[4], pbv[4];
#pragma unroll
  for (int k = 0; k < 4; ++k) {
    int e = base + k * 1024 + t;
    dstv[k] = -1;
    if (e < E_EDGES) {
      int src, dst;
      if (f) {
        src = ((const int*)ei)[e];
        dst = ((const int*)ei)[E_EDGES + e];
      } else {
        src = (int)(((const long long*)ei)[e]);
        dst = (int)(((const long long*)ei)[E_EDGES + e]);
      }
      float4 sd = *(const float4*)(s1 + (size_t)dst * 4);
      float4 ss = *(const float4*)(s2 + (size_t)src * 4);
      float ea[16];
#pragma unroll
      for (int i = 0; i < 4; i++) {
        float4 v = *(const float4*)(edge_attr + (size_t)e * 16 + i * 4);
        ea[4 * i] = v.x; ea[4 * i + 1] = v.y; ea[4 * i + 2] = v.z; ea[4 * i + 3] = v.w;
      }
      float ex[4];
#pragma unroll
      for (int h = 0; h < 4; h++) {
        float d = 0.f;
#pragma unroll
        for (int i = 0; i < 16; i++) d += ea[i] * w3[h * 16 + i];
        float v = (&sd.x)[h] + (&ss.x)[h] + d;
        v = (v >= 0.f) ? v : NEG_SLOPE * v;
        ex[h] = __expf(v);
      }
      dstv[k] = dst;
      srcv[k] = src;
      pav[k] = ((unsigned int)f2bf(ex[1]) << 16) | (unsigned int)f2bf(ex[0]);
      pbv[k] = ((unsigned int)f2bf(ex[3]) << 16) | (unsigned int)f2bf(ex[2]);
      atomicAdd(&cnt[dst >> BK_SH], 1);
    }
  }
  __syncthreads();
  for (int i = t; i < NBUCK; i += 1024) {
    int c = cnt[i];
    if (c) rb[i] = atomicAdd(&bcur[i], c);
  }
  __syncthreads();
#pragma unroll
  for (int k = 0; k < 4; ++k) {
    if (dstv[k] >= 0) {
      int bk = dstv[k] >> BK_SH;
      int slot = rb[bk] + atomicAdd(&cur[bk], 1);
      if (slot < CAPS) {
        evs[(size_t)bk * CAPS + slot] = make_uint4((unsigned int)srcv[k], pav[k], pbv[k],
                                                   (unsigned int)(dstv[k] & 63));
      } else {
        int oi = atomicAdd(ovfc, 1);
        if (oi < OVF_MAX)
          ovf[oi] = make_uint4((unsigned int)srcv[k], pav[k], pbv[k],
                               (unsigned int)dstv[k]);  // full dst
      }
    }
  }
}

// ---- one block (256 thr, 4 waves) per 64-node bucket. Staging packs
//      (w bf16 | w*scl bf16) per head into one u32 (register-only, NO atomics).
//      Inner loop per edge: ONE broadcast ds_read_b32 + ONE 4B gather +
//      2 shifts + den/dws adds + 4 ubyte-FMAs. Bias removed via dws at end.
__global__ __launch_bounds__(256) void k_aggr(const int* __restrict__ bcur,
    const uint4* __restrict__ evs, const uint4* __restrict__ ovf,
    const int* __restrict__ ovfc, const unsigned int* __restrict__ xwq,
    const float* __restrict__ scl4, unsigned short* __restrict__ out_hb) {
  __shared__ int lsrc[CAP];
  __shared__ unsigned int lwp[4][CAPP];
  __shared__ int cnt[64], bs[64], cur[64];
  __shared__ int onS;
  const int b = blockIdx.x;
  const int t = threadIdx.x;
  const size_t e0 = (size_t)b * CAPS;
  const int ne = bcur[b];
  const int stored = (ne < CAPS) ? ne : CAPS;
  if (t < 64) { cnt[t] = 0; cur[t] = 0; }
  if (t == 0) {
    int on = *ovfc;
    onS = (on < 0) ? 0 : ((on > OVF_MAX) ? OVF_MAX : on);
  }
  __syncthreads();
  const int on = onS;
  const bool ok = (stored <= CAP);
  if (ok) {
    uint4 rv[5];
#pragma unroll
    for (int k = 0; k < 5; ++k) {
      int i = k * 256 + t;
      if (i < stored) {
        rv[k] = evs[e0 + i];
        atomicAdd(&cnt[rv[k].w], 1);
      }
    }
    __syncthreads();
    if (t < 64) bs[t] = cnt[t];
    __syncthreads();
    for (int off = 1; off < 64; off <<= 1) {
      int x = 0;
      if (t < 64 && t >= off) x = bs[t - off];
      __syncthreads();
      if (t < 64) bs[t] += x;
      __syncthreads();
    }
#pragma unroll
    for (int k = 0; k < 5; ++k) {
      int i = k * 256 + t;
      if (i < stored) {
        int ld = rv[k].w;
        int slot = bs[ld] - cnt[ld] + atomicAdd(&cur[ld], 1);
        lsrc[slot] = (int)rv[k].x;
        float4 sc = *(const float4*)(scl4 + (size_t)rv[k].x * 4);
        float w0 = asf(rv[k].y << 16), w1 = asf(rv[k].y & 0xFFFF0000u);
        float w2 = asf(rv[k].z << 16), w3_ = asf(rv[k].z & 0xFFFF0000u);
        // pack: low16 = bf16(w) (for den), high16 = bf16(w*scl) (for acc/dws)
        lwp[0][slot] = (unsigned int)f2bf(w0) | ((unsigned int)f2bf(w0 * sc.x) << 16);
        lwp[1][slot] = (unsigned int)f2bf(w1) | ((unsigned int)f2bf(w1 * sc.y) << 16);
        lwp[2][slot] = (unsigned int)f2bf(w2) | ((unsigned int)f2bf(w2 * sc.z) << 16);
        lwp[3][slot] = (unsigned int)f2bf(w3_) | ((unsigned int)f2bf(w3_ * sc.w) << 16);
      }
    }
    __syncthreads();
  }

  const int wv = t >> 6, lane = t & 63;
  const int hsel = lane >> 4;         // head owned by this lane
  const bool hlo2 = (hsel < 2);
  const bool hodd = (hsel & 1);
  const unsigned int* lwsel = lwp[hsel];

#define EDGE_P(p_, u_)                                                    \
  {                                                                       \
    den += asf((p_) << 16);                                               \
    float ws = asf((p_) & 0xFFFF0000u);                                   \
    dws += ws;                                                            \
    acc0 += ws * (float)((u_) & 0xFFu);                                   \
    acc1 += ws * (float)(((u_) >> 8) & 0xFFu);                            \
    acc2 += ws * (float)(((u_) >> 16) & 0xFFu);                           \
    acc3 += ws * (float)((u_) >> 24);                                     \
  }
#define EDGE_SLOW(w_, sc_, u_)                                            \
  {                                                                       \
    den += (w_);                                                          \
    float ws = (w_) * (sc_);                                              \
    dws += ws;                                                            \
    acc0 += ws * (float)((u_) & 0xFFu);                                   \
    acc1 += ws * (float)(((u_) >> 8) & 0xFFu);                            \
    acc2 += ws * (float)(((u_) >> 16) & 0xFFu);                           \
    acc3 += ws * (float)((u_) >> 24);                                     \
  }

  for (int r = 0; r < 16; ++r) {
    const int ln = wv * 16 + r;
    const int n = b * 64 + ln;
    if (n >= N_NODES) break;
    float acc0 = 0.f, acc1 = 0.f, acc2 = 0.f, acc3 = 0.f, den = 0.f, dws = 0.f;
    if (ok) {
      const int je = bs[ln];
      int j = je - cnt[ln];
      for (; j + 4 <= je; j += 4) {
        int s0 = lsrc[j], s1_ = lsrc[j + 1], s2_ = lsrc[j + 2], s3_ = lsrc[j + 3];
        unsigned int p0 = lwsel[j], p1 = lwsel[j + 1], p2 = lwsel[j + 2], p3 = lwsel[j + 3];
        unsigned int u0 = xwq[(size_t)s0 * 64 + lane];
        unsigned int u1 = xwq[(size_t)s1_ * 64 + lane];
        unsigned int u2 = xwq[(size_t)s2_ * 64 + lane];
        unsigned int u3 = xwq[(size_t)s3_ * 64 + lane];
        EDGE_P(p0, u0);
        EDGE_P(p1, u1);
        EDGE_P(p2, u2);
        EDGE_P(p3, u3);
      }
      for (; j < je; ++j) {
        int s0 = lsrc[j];
        unsigned int p0 = lwsel[j];
        unsigned int u0 = xwq[(size_t)s0 * 64 + lane];
        EDGE_P(p0, u0);
      }
    } else {
      // rare fallback (bucket staged > CAP): predicate scan over stored slots
      for (int i = 0; i < stored; ++i) {
        uint4 v0 = evs[e0 + i];
        if ((int)v0.w == ln) {
          unsigned int wp = hlo2 ? v0.y : v0.z;
          float w0 = hodd ? asf(wp & 0xFFFF0000u) : asf(wp << 16);
          float c0 = scl4[(size_t)v0.x * 4 + hsel];
          unsigned int u0 = xwq[(size_t)v0.x * 64 + lane];
          EDGE_SLOW(w0, c0, u0);
        }
      }
    }
    // overflow list (normally empty)
    for (int i = 0; i < on; ++i) {
      uint4 v0 = ovf[i];
      if ((int)v0.w == n) {
        unsigned int wp = hlo2 ? v0.y : v0.z;
        float w0 = hodd ? asf(wp & 0xFFFF0000u) : asf(wp << 16);
        float c0 = scl4[(size_t)v0.x * 4 + hsel];
        unsigned int u0 = xwq[(size_t)v0.x * 64 + lane];
        EDGE_SLOW(w0, c0, u0);
      }
    }
    float d = den + 1e-16f;
    float base = 128.f * dws;
    uint2 o;
    o.x = ((unsigned int)f2bf((acc1 - base) / d) << 16) | (unsigned int)f2bf((acc0 - base) / d);
    o.y = ((unsigned int)f2bf((acc3 - base) / d) << 16) | (unsigned int)f2bf((acc2 - base) / d);
    *(uint2*)(out_hb + (size_t)n * 256 + lane * 4) = o;
  }
#undef EDGE_P
#undef EDGE_SLOW
}

// ---- out = elu(out_hb @ Pt^T + bias). B-register double-buffer; epilogue goes
//      through LDS transpose (aliases dead As) -> float4 stores; __expf ELU.
__global__ __launch_bounds__(256, 4) void k_gemm_out(const unsigned short* __restrict__ A,
    const unsigned short* __restrict__ Pt, const float* __restrict__ bias,
    float* __restrict__ out) {
  __shared__ __align__(16) char smem[32768];
  unsigned short* As = (unsigned short*)smem;
  float* Ls = (float*)smem;  // aliases As; used after MFMA loop (16x260 fp32 = 16.6KB)
  const int bm = blockIdx.x * 64;
  const int t = threadIdx.x;

#pragma unroll
  for (int i = 0; i < 8; ++i) {
    int c = i * 256 + t;
    int row = c >> 5, G = c & 31;
    short8 v = (short8){0, 0, 0, 0, 0, 0, 0, 0};
    if (bm + row < N_NODES) v = *(const short8*)(A + (size_t)(bm + row) * 256 + G * 8);
    int phys = row * 512 + ((G ^ (row & 7)) << 4);
    *(short8*)((char*)As + phys) = v;
  }
  __syncthreads();

  const int wave = t >> 6;
  const int lane = t & 63;
  const int l16 = lane & 15, lg = lane >> 4;
  const int colbase = wave * 64;
  f32x4 acc[4][4];
#pragma unroll
  for (int i = 0; i < 4; i++)
#pragma unroll
    for (int j = 0; j < 4; j++) acc[i][j] = (f32x4){0.f, 0.f, 0.f, 0.f};

  short8 bcur[4], bnxt[4];
#pragma unroll
  for (int ni = 0; ni < 4; ni++)
    bcur[ni] = *(const short8*)(Pt + (colbase + ni * 16 + l16) * 256 + lg * 8);

#pragma unroll
  for (int ks = 0; ks < 8; ++ks) {
    short8 a[4];
#pragma unroll
    for (int mi = 0; mi < 4; mi++) {
      int row = mi * 16 + l16;
      int phys = row * 512 + (((ks * 4 + lg) ^ (row & 7)) << 4);
      a[mi] = *(const short8*)((const char*)As + phys);
    }
    if (ks < 7) {
      const int k0n = (ks + 1) * 32 + lg * 8;
#pragma unroll
      for (int ni = 0; ni < 4; ni++)
        bnxt[ni] = *(const short8*)(Pt + (colbase + ni * 16 + l16) * 256 + k0n);
    }
#pragma unroll
    for (int mi = 0; mi < 4; mi++)
#pragma unroll
      for (int ni = 0; ni < 4; ni++)
        acc[mi][ni] = __builtin_amdgcn_mfma_f32_16x16x32_bf16(a[mi], bcur[ni], acc[mi][ni], 0, 0, 0);
#pragma unroll
    for (int ni = 0; ni < 4; ni++) bcur[ni] = bnxt[ni];
  }

  // epilogue: per 16-row tile, transpose through LDS, then coalesced float4 stores
  const int row16 = t >> 4;   // 0..15
  const int q = t & 15;       // float4-column group base
#pragma unroll
  for (int mi = 0; mi < 4; mi++) {
    __syncthreads();  // Ls free (As dead / previous read done)
#pragma unroll
    for (int r = 0; r < 4; r++) {
#pragma unroll
      for (int ni = 0; ni < 4; ni++)
        Ls[(lg * 4 + r) * 260 + colbase + ni * 16 + l16] = acc[mi][ni][r];
    }
    __syncthreads();
    int grow = bm + mi * 16 + row16;
    if (grow < N_NODES) {
#pragma unroll
      for (int k = 0; k < 4; ++k) {
        int qc = (q + k * 16) * 4;  // float column 0..252
        float4 v = *(const float4*)&Ls[row16 * 260 + qc];
        float4 bv = *(const float4*)(bias + qc);
        v.x += bv.x; v.y += bv.y; v.z += bv.z; v.w += bv.w;
        v.x = (v.x > 0.f) ? v.x : (__expf(v.x) - 1.f);
        v.y = (v.y > 0.f) ? v.y : (__expf(v.y) - 1.f);
        v.z = (v.z > 0.f) ? v.z : (__expf(v.z) - 1.f);
        v.w = (v.w > 0.f) ? v.w : (__expf(v.w) - 1.f);
        *(float4*)(out + (size_t)grow * 256 + qc) = v;
      }
    }
  }
}

extern "C" void kernel_launch(void* const* d_in, const int* in_sizes, int n_in,
                              void* d_out, int out_size, void* d_ws, size_t ws_size,
                              hipStream_t stream) {
  const float* x = (const float*)d_in[0];
  const void* ei = d_in[1];
  const float* edge_attr = (const float*)d_in[2];
  const float* W = (const float*)d_in[3];
  const float* W_edge = (const float*)d_in[4];
  const float* att = (const float*)d_in[5];
  const float* proj_w = (const float*)d_in[6];
  const float* proj_b = (const float*)d_in[7];
  float* out = (float*)d_out;

  char* ws = (char*)d_ws;
  size_t off = 0;
  auto alloc = [&](size_t bytes) -> void* {
    void* p = (void*)(ws + off);
    off += (bytes + 255) & ~(size_t)255;
    return p;
  };
  unsigned int* xwq     = (unsigned int*)alloc((size_t)N_NODES * 256);
  float* scl4    = (float*)alloc((size_t)N_NODES * 4 * 4);
  unsigned short* outhb = (unsigned short*)alloc((size_t)N_NODES * 256 * 2);
  float* s1      = (float*)alloc((size_t)N_NODES * 4 * 4);
  float* s2      = (float*)alloc((size_t)N_NODES * 4 * 4);
  uint4* evs     = (uint4*)alloc((size_t)NBUCK * CAPS * 16);
  uint4* ovf     = (uint4*)alloc((size_t)OVF_MAX * 16);
  int* bcur      = (int*)alloc((size_t)(NBUCK + 64) * 4);
  int* ovfc      = bcur + NBUCK;
  unsigned short* Bt = (unsigned short*)alloc(65536 * 2);
  unsigned short* Pt = (unsigned short*)alloc(65536 * 2);
  float* w3      = (float*)alloc(64 * 4);
  int* flag      = (int*)alloc(256);

  const int NB_E = (E_EDGES + 4095) / 4096;  // 391

  hipMemsetAsync(bcur, 0, (size_t)(NBUCK + 64) * 4, stream);
  k_detect<<<1, 64, 0, stream>>>(ei, flag);
  k_prep<<<(131136 + 255) / 256, 256, 0, stream>>>(W, proj_w, W_edge, att, Bt, Pt, w3);
  k_gemm_x<<<(N_NODES + 63) / 64, 256, 0, stream>>>(x, Bt, att, xwq, scl4, s1, s2);
  k_edge<<<NB_E, 1024, 0, stream>>>(ei, flag, edge_attr, s1, s2, w3, bcur, evs, ovf, ovfc);
  k_aggr<<<NBUCK, 256, 0, stream>>>(bcur, evs, ovf, ovfc, xwq, scl4, outhb);
  k_gemm_out<<<(N_NODES + 63) / 64, 256, 0, stream>>>(outhb, Pt, proj_b, out);
}

// Round 20
// 290.222 us; speedup vs baseline: 1.0527x; 1.0527x over previous
//
#include <hip/hip_runtime.h>
#include <hip/hip_bf16.h>
#include <stdint.h>

#define N_NODES 100000
#define E_EDGES 1600000
#define NEG_SLOPE 0.2f
#define NBUCK 1563     // ceil(N/64): bucket = 64 consecutive dst nodes
#define BK_SH 6
#define CAPS 2048      // fixed global evs slots per bucket (mean 1024, ~30 sigma)
#define CAP 1536       // LDS staging cap per bucket in k_aggr
#define OVF_MAX 8192

typedef short short8 __attribute__((ext_vector_type(8)));
typedef float f32x4 __attribute__((ext_vector_type(4)));

__device__ __forceinline__ unsigned short f2bf(float f) {
  union { float f; unsigned int u; } c; c.f = f;
  unsigned int u = c.u;
  unsigned int r = u + 0x7FFFu + ((u >> 16) & 1u);
  return (unsigned short)(r >> 16);
}
__device__ __forceinline__ float asf(unsigned int u) {
  union { unsigned int u; float f; } c; c.u = u;
  return c.f;
}

// ---- detect int32 vs int64 edge_index: int64 => odd int32 words are all 0
__global__ void k_detect(const void* ei, int* flag) {
  int t = threadIdx.x;
  int v = ((const int*)ei)[2 * t + 1];
  unsigned long long b = __ballot(v != 0);
  if (t == 0) *flag = (b != 0ull) ? 1 : 0;  // 1 = int32 layout
}

// ---- pack W -> Bt[col][k] bf16, proj_w -> Pt[col][k] bf16 (identity layout),
//      w3[h][d] = sum_o W_edge[h][d][o]*a3[h][o]
__global__ void k_prep(const float* __restrict__ W, const float* __restrict__ proj_w,
                       const float* __restrict__ W_edge, const float* __restrict__ att,
                       unsigned short* __restrict__ Bt, unsigned short* __restrict__ Pt,
                       float* __restrict__ w3) {
  int t = blockIdx.x * 256 + threadIdx.x;
  if (t < 65536) {
    int col = t >> 8, k = t & 255;
    int h = col >> 6, o = col & 63;
    Bt[t] = f2bf(W[h * 16384 + k * 64 + o]);
  } else if (t < 131072) {
    int t2 = t - 65536;
    int o = t2 >> 8, i = t2 & 255;
    Pt[t2] = f2bf(proj_w[i * 256 + o]);
  } else if (t < 131136) {
    int t3 = t - 131072;
    int h = t3 >> 4, d = t3 & 15;
    float s = 0.f;
    for (int o = 0; o < 64; ++o)
      s += W_edge[h * 1024 + d * 64 + o] * att[h * 192 + 128 + o];
    w3[t3] = s;
  }
}

// ---- GEMM + fused epilogue (scores s1/s2, per-(row,head) BIASED-UNSIGNED int8
//      quant: byte = rn(127*v/mx) + 128) via LDS-transpose epilogue.
//      B-register double-buffered.
__global__ __launch_bounds__(256, 4) void k_gemm_x(const float* __restrict__ x,
    const unsigned short* __restrict__ Bt, const float* __restrict__ att,
    unsigned int* __restrict__ xwq, float* __restrict__ scl4,
    float* __restrict__ s1, float* __restrict__ s2) {
  __shared__ __align__(16) char smem[32768];
  unsigned short* As = (unsigned short*)smem;
  float* Ls = (float*)smem;                    // epilogue transpose, 16x260 fp32
  float* attS = (float*)(smem + 24576);        // 768 floats, above Ls region
  const int bm = blockIdx.x * 64;
  const int t = threadIdx.x;

#pragma unroll
  for (int i = 0; i < 16; ++i) {
    int c = i * 256 + t;
    int row = c >> 6, f4 = c & 63;
    uint2 w = make_uint2(0u, 0u);
    if (bm + row < N_NODES) {
      float4 v = *(const float4*)(x + (size_t)(bm + row) * 256 + f4 * 4);
      w.x = (unsigned int)f2bf(v.x) | ((unsigned int)f2bf(v.y) << 16);
      w.y = (unsigned int)f2bf(v.z) | ((unsigned int)f2bf(v.w) << 16);
    }
    int phys = row * 512 + (((f4 >> 1) ^ (row & 7)) << 4) + ((f4 & 1) << 3);
    *(uint2*)((char*)As + phys) = w;
  }
  __syncthreads();

  const int wave = t >> 6;
  const int lane = t & 63;
  const int l16 = lane & 15, lg = lane >> 4;
  const int colbase = wave * 64;
  f32x4 acc[4][4];
#pragma unroll
  for (int i = 0; i < 4; i++)
#pragma unroll
    for (int j = 0; j < 4; j++) acc[i][j] = (f32x4){0.f, 0.f, 0.f, 0.f};

  short8 bcur[4], bnxt[4];
#pragma unroll
  for (int ni = 0; ni < 4; ni++)
    bcur[ni] = *(const short8*)(Bt + (colbase + ni * 16 + l16) * 256 + lg * 8);

#pragma unroll
  for (int ks = 0; ks < 8; ++ks) {
    short8 a[4];
#pragma unroll
    for (int mi = 0; mi < 4; mi++) {
      int row = mi * 16 + l16;
      int phys = row * 512 + (((ks * 4 + lg) ^ (row & 7)) << 4);
      a[mi] = *(const short8*)((const char*)As + phys);
    }
    if (ks < 7) {
      const int k0n = (ks + 1) * 32 + lg * 8;
#pragma unroll
      for (int ni = 0; ni < 4; ni++)
        bnxt[ni] = *(const short8*)(Bt + (colbase + ni * 16 + l16) * 256 + k0n);
    }
#pragma unroll
    for (int mi = 0; mi < 4; mi++)
#pragma unroll
      for (int ni = 0; ni < 4; ni++)
        acc[mi][ni] = __builtin_amdgcn_mfma_f32_16x16x32_bf16(a[mi], bcur[ni], acc[mi][ni], 0, 0, 0);
#pragma unroll
    for (int ni = 0; ni < 4; ni++) bcur[ni] = bnxt[ni];
  }

  // all waves done reading As before attS (aliased) is written
  __syncthreads();
  for (int i = t; i < 768; i += 256) attS[i] = att[i];

  const int row16 = t >> 4;     // row within 16-row tile
  const int g = t & 15;         // 16-col group; head h = g>>2
  const int h = g >> 2;
  const int cwh = (g & 3) * 16; // col offset within head
#pragma unroll
  for (int mi = 0; mi < 4; mi++) {
    __syncthreads();
#pragma unroll
    for (int r = 0; r < 4; r++)
#pragma unroll
      for (int ni = 0; ni < 4; ni++)
        Ls[(lg * 4 + r) * 260 + colbase + ni * 16 + l16] = acc[mi][ni][r];
    __syncthreads();
    float v[16];
#pragma unroll
    for (int k = 0; k < 4; ++k) {
      float4 f = *(const float4*)&Ls[row16 * 260 + g * 16 + k * 4];
      v[4 * k] = f.x; v[4 * k + 1] = f.y; v[4 * k + 2] = f.z; v[4 * k + 3] = f.w;
    }
    float mx = 0.f, p1 = 0.f, p2 = 0.f;
#pragma unroll
    for (int j = 0; j < 16; ++j) {
      mx = fmaxf(mx, fabsf(v[j]));
      p1 += v[j] * attS[h * 192 + cwh + j];
      p2 += v[j] * attS[h * 192 + 64 + cwh + j];
    }
    mx = fmaxf(mx, __shfl_xor(mx, 1, 64));
    mx = fmaxf(mx, __shfl_xor(mx, 2, 64));
    p1 += __shfl_xor(p1, 1, 64); p1 += __shfl_xor(p1, 2, 64);
    p2 += __shfl_xor(p2, 1, 64); p2 += __shfl_xor(p2, 2, 64);
    int row = bm + mi * 16 + row16;
    if (row < N_NODES) {
      mx += 1e-30f;
      float inv = 127.f / mx;
      uint4 pk;
      unsigned int* pw = &pk.x;
#pragma unroll
      for (int k = 0; k < 4; ++k) {
        unsigned int q0 = (unsigned int)(__float2int_rn(v[4 * k] * inv) + 128);
        unsigned int q1 = (unsigned int)(__float2int_rn(v[4 * k + 1] * inv) + 128);
        unsigned int q2 = (unsigned int)(__float2int_rn(v[4 * k + 2] * inv) + 128);
        unsigned int q3 = (unsigned int)(__float2int_rn(v[4 * k + 3] * inv) + 128);
        pw[k] = q0 | (q1 << 8) | (q2 << 16) | (q3 << 24);
      }
      *(uint4*)(xwq + (size_t)row * 64 + g * 4) = pk;
      if ((g & 3) == 0) {
        scl4[row * 4 + h] = mx * (1.f / 127.f);
        s1[row * 4 + h] = p1;
        s2[row * 4 + h] = p2;
      }
    }
  }
}

// ---- per-edge compute + bucket-partitioned scatter into FIXED 2048-slot bucket
//      regions. Block-private runs via one atomicAdd(bcur[bk], c); overflow
//      spills to global ovf list.
__global__ __launch_bounds__(1024) void k_edge(const void* ei, const int* __restrict__ flag,
                       const float* __restrict__ edge_attr,
                       const float* __restrict__ s1, const float* __restrict__ s2,
                       const float* __restrict__ w3g, int* __restrict__ bcur,
                       uint4* __restrict__ evs, uint4* __restrict__ ovf,
                       int* __restrict__ ovfc) {
  __shared__ float w3[64];
  __shared__ int cnt[NBUCK];
  __shared__ int rb[NBUCK];
  __shared__ int cur[NBUCK];
  const int t = threadIdx.x;
  for (int i = t; i < NBUCK; i += 1024) { cnt[i] = 0; cur[i] = 0; }
  if (t < 64) w3[t] = w3g[t];
  __syncthreads();

  const int f = *flag;
  const int base = blockIdx.x * 4096;
  int dstv[4], srcv[4];
  unsigned int pav[4], pbv[4];
#pragma unroll
  for (int k = 0; k < 4; ++k) {
    int e = base + k * 1024 + t;
    dstv[k] = -1;
    if (e < E_EDGES) {
      int src, dst;
      if (f) {
        src = ((const int*)ei)[e];
        dst = ((const int*)ei)[E_EDGES + e];
      } else {
        src = (int)(((const long long*)ei)[e]);
        dst = (int)(((const long long*)ei)[E_EDGES + e]);
      }
      float4 sd = *(const float4*)(s1 + (size_t)dst * 4);
      float4 ss = *(const float4*)(s2 + (size_t)src * 4);
      float ea[16];
#pragma unroll
      for (int i = 0; i < 4; i++) {
        float4 v = *(const float4*)(edge_attr + (size_t)e * 16 + i * 4);
        ea[4 * i] = v.x; ea[4 * i + 1] = v.y; ea[4 * i + 2] = v.z; ea[4 * i + 3] = v.w;
      }
      float ex[4];
#pragma unroll
      for (int h = 0; h < 4; h++) {
        float d = 0.f;
#pragma unroll
        for (int i = 0; i < 16; i++) d += ea[i] * w3[h * 16 + i];
        float v = (&sd.x)[h] + (&ss.x)[h] + d;
        v = (v >= 0.f) ? v : NEG_SLOPE * v;
        ex[h] = __expf(v);
      }
      dstv[k] = dst;
      srcv[k] = src;
      pav[k] = ((unsigned int)f2bf(ex[1]) << 16) | (unsigned int)f2bf(ex[0]);
      pbv[k] = ((unsigned int)f2bf(ex[3]) << 16) | (unsigned int)f2bf(ex[2]);
      atomicAdd(&cnt[dst >> BK_SH], 1);
    }
  }
  __syncthreads();
  for (int i = t; i < NBUCK; i += 1024) {
    int c = cnt[i];
    if (c) rb[i] = atomicAdd(&bcur[i], c);
  }
  __syncthreads();
#pragma unroll
  for (int k = 0; k < 4; ++k) {
    if (dstv[k] >= 0) {
      int bk = dstv[k] >> BK_SH;
      int slot = rb[bk] + atomicAdd(&cur[bk], 1);
      if (slot < CAPS) {
        evs[(size_t)bk * CAPS + slot] = make_uint4((unsigned int)srcv[k], pav[k], pbv[k],
                                                   (unsigned int)(dstv[k] & 63));
      } else {
        int oi = atomicAdd(ovfc, 1);
        if (oi < OVF_MAX)
          ovf[oi] = make_uint4((unsigned int)srcv[k], pav[k], pbv[k],
                               (unsigned int)dstv[k]);  // full dst
      }
    }
  }
}

// ---- one block (256 thr, 4 waves) per 64-node bucket. Inner loop per edge:
//      ds_read_u16 (head-major bf16 weight) + scl4 broadcast + ONE 4B gather,
//      ubyte-cvt unpack (biased-unsigned int8), bias removed via dws accumulator.
__global__ __launch_bounds__(256) void k_aggr(const int* __restrict__ bcur,
    const uint4* __restrict__ evs, const uint4* __restrict__ ovf,
    const int* __restrict__ ovfc, const unsigned int* __restrict__ xwq,
    const float* __restrict__ scl4, unsigned short* __restrict__ out_hb) {
  __shared__ int lsrc[CAP];
  __shared__ unsigned short lwh[4][CAP];
  __shared__ int cnt[64], bs[64], cur[64];
  __shared__ int onS;
  const int b = blockIdx.x;
  const int t = threadIdx.x;
  const size_t e0 = (size_t)b * CAPS;
  const int ne = bcur[b];
  const int stored = (ne < CAPS) ? ne : CAPS;
  if (t < 64) { cnt[t] = 0; cur[t] = 0; }
  if (t == 0) {
    int on = *ovfc;
    onS = (on < 0) ? 0 : ((on > OVF_MAX) ? OVF_MAX : on);
  }
  __syncthreads();
  const int on = onS;
  const bool ok = (stored <= CAP);
  if (ok) {
    uint4 rv[6];
#pragma unroll
    for (int k = 0; k < 6; ++k) {
      int i = k * 256 + t;
      if (i < stored) {
        rv[k] = evs[e0 + i];
        atomicAdd(&cnt[rv[k].w], 1);
      }
    }
    __syncthreads();
    if (t < 64) bs[t] = cnt[t];
    __syncthreads();
    for (int off = 1; off < 64; off <<= 1) {
      int x = 0;
      if (t < 64 && t >= off) x = bs[t - off];
      __syncthreads();
      if (t < 64) bs[t] += x;
      __syncthreads();
    }
#pragma unroll
    for (int k = 0; k < 6; ++k) {
      int i = k * 256 + t;
      if (i < stored) {
        int ld = rv[k].w;
        int slot = bs[ld] - cnt[ld] + atomicAdd(&cur[ld], 1);
        lsrc[slot] = (int)rv[k].x;
        lwh[0][slot] = (unsigned short)(rv[k].y & 0xFFFFu);
        lwh[1][slot] = (unsigned short)(rv[k].y >> 16);
        lwh[2][slot] = (unsigned short)(rv[k].z & 0xFFFFu);
        lwh[3][slot] = (unsigned short)(rv[k].z >> 16);
      }
    }
    __syncthreads();
  }

  const int wv = t >> 6, lane = t & 63;
  const int hsel = lane >> 4;         // head owned by this lane
  const bool hlo2 = (hsel < 2);
  const bool hodd = (hsel & 1);
  const unsigned short* lwsel = lwh[hsel];

#define EDGE_CORE(w_, sc_, u_)                                            \
  {                                                                       \
    den += (w_);                                                          \
    float ws = (w_) * (sc_);                                              \
    dws += ws;                                                            \
    acc0 += ws * (float)((u_) & 0xFFu);                                   \
    acc1 += ws * (float)(((u_) >> 8) & 0xFFu);                            \
    acc2 += ws * (float)(((u_) >> 16) & 0xFFu);                           \
    acc3 += ws * (float)((u_) >> 24);                                     \
  }

  for (int r = 0; r < 16; ++r) {
    const int ln = wv * 16 + r;
    const int n = b * 64 + ln;
    if (n >= N_NODES) break;
    float acc0 = 0.f, acc1 = 0.f, acc2 = 0.f, acc3 = 0.f, den = 0.f, dws = 0.f;
    if (ok) {
      const int je = bs[ln];
      int j = je - cnt[ln];
      for (; j + 4 <= je; j += 4) {
        int s0 = lsrc[j], s1_ = lsrc[j + 1], s2_ = lsrc[j + 2], s3_ = lsrc[j + 3];
        float w0 = asf((unsigned int)lwsel[j] << 16);
        float w1 = asf((unsigned int)lwsel[j + 1] << 16);
        float w2 = asf((unsigned int)lwsel[j + 2] << 16);
        float w3_ = asf((unsigned int)lwsel[j + 3] << 16);
        float c0 = scl4[(size_t)s0 * 4 + hsel];
        float c1 = scl4[(size_t)s1_ * 4 + hsel];
        float c2 = scl4[(size_t)s2_ * 4 + hsel];
        float c3 = scl4[(size_t)s3_ * 4 + hsel];
        unsigned int u0 = xwq[(size_t)s0 * 64 + lane];
        unsigned int u1 = xwq[(size_t)s1_ * 64 + lane];
        unsigned int u2 = xwq[(size_t)s2_ * 64 + lane];
        unsigned int u3 = xwq[(size_t)s3_ * 64 + lane];
        EDGE_CORE(w0, c0, u0);
        EDGE_CORE(w1, c1, u1);
        EDGE_CORE(w2, c2, u2);
        EDGE_CORE(w3_, c3, u3);
      }
      for (; j < je; ++j) {
        int s0 = lsrc[j];
        float w0 = asf((unsigned int)lwsel[j] << 16);
        float c0 = scl4[(size_t)s0 * 4 + hsel];
        unsigned int u0 = xwq[(size_t)s0 * 64 + lane];
        EDGE_CORE(w0, c0, u0);
      }
    } else {
      // rare fallback (bucket staged > CAP): predicate scan over stored slots
      for (int i = 0; i < stored; ++i) {
        uint4 v0 = evs[e0 + i];
        if ((int)v0.w == ln) {
          unsigned int wp = hlo2 ? v0.y : v0.z;
          float w0 = hodd ? asf(wp & 0xFFFF0000u) : asf(wp << 16);
          float c0 = scl4[(size_t)v0.x * 4 + hsel];
          unsigned int u0 = xwq[(size_t)v0.x * 64 + lane];
          EDGE_CORE(w0, c0, u0);
        }
      }
    }
    // overflow list (normally empty)
    for (int i = 0; i < on; ++i) {
      uint4 v0 = ovf[i];
      if ((int)v0.w == n) {
        unsigned int wp = hlo2 ? v0.y : v0.z;
        float w0 = hodd ? asf(wp & 0xFFFF0000u) : asf(wp << 16);
        float c0 = scl4[(size_t)v0.x * 4 + hsel];
        unsigned int u0 = xwq[(size_t)v0.x * 64 + lane];
        EDGE_CORE(w0, c0, u0);
      }
    }
    float d = den + 1e-16f;
    float base = 128.f * dws;
    uint2 o;
    o.x = ((unsigned int)f2bf((acc1 - base) / d) << 16) | (unsigned int)f2bf((acc0 - base) / d);
    o.y = ((unsigned int)f2bf((acc3 - base) / d) << 16) | (unsigned int)f2bf((acc2 - base) / d);
    *(uint2*)(out_hb + (size_t)n * 256 + lane * 4) = o;
  }
#undef EDGE_CORE
}

// ---- out = elu(out_hb @ Pt^T + bias). B-register double-buffer; epilogue goes
//      through LDS transpose (aliases dead As) -> float4 stores; __expf ELU.
__global__ __launch_bounds__(256, 4) void k_gemm_out(const unsigned short* __restrict__ A,
    const unsigned short* __restrict__ Pt, const float* __restrict__ bias,
    float* __restrict__ out) {
  __shared__ __align__(16) char smem[32768];
  unsigned short* As = (unsigned short*)smem;
  float* Ls = (float*)smem;  // aliases As; used after MFMA loop (16x260 fp32 = 16.6KB)
  const int bm = blockIdx.x * 64;
  const int t = threadIdx.x;

#pragma unroll
  for (int i = 0; i < 8; ++i) {
    int c = i * 256 + t;
    int row = c >> 5, G = c & 31;
    short8 v = (short8){0, 0, 0, 0, 0, 0, 0, 0};
    if (bm + row < N_NODES) v = *(const short8*)(A + (size_t)(bm + row) * 256 + G * 8);
    int phys = row * 512 + ((G ^ (row & 7)) << 4);
    *(short8*)((char*)As + phys) = v;
  }
  __syncthreads();

  const int wave = t >> 6;
  const int lane = t & 63;
  const int l16 = lane & 15, lg = lane >> 4;
  const int colbase = wave * 64;
  f32x4 acc[4][4];
#pragma unroll
  for (int i = 0; i < 4; i++)
#pragma unroll
    for (int j = 0; j < 4; j++) acc[i][j] = (f32x4){0.f, 0.f, 0.f, 0.f};

  short8 bcur[4], bnxt[4];
#pragma unroll
  for (int ni = 0; ni < 4; ni++)
    bcur[ni] = *(const short8*)(Pt + (colbase + ni * 16 + l16) * 256 + lg * 8);

#pragma unroll
  for (int ks = 0; ks < 8; ++ks) {
    short8 a[4];
#pragma unroll
    for (int mi = 0; mi < 4; mi++) {
      int row = mi * 16 + l16;
      int phys = row * 512 + (((ks * 4 + lg) ^ (row & 7)) << 4);
      a[mi] = *(const short8*)((const char*)As + phys);
    }
    if (ks < 7) {
      const int k0n = (ks + 1) * 32 + lg * 8;
#pragma unroll
      for (int ni = 0; ni < 4; ni++)
        bnxt[ni] = *(const short8*)(Pt + (colbase + ni * 16 + l16) * 256 + k0n);
    }
#pragma unroll
    for (int mi = 0; mi < 4; mi++)
#pragma unroll
      for (int ni = 0; ni < 4; ni++)
        acc[mi][ni] = __builtin_amdgcn_mfma_f32_16x16x32_bf16(a[mi], bcur[ni], acc[mi][ni], 0, 0, 0);
#pragma unroll
    for (int ni = 0; ni < 4; ni++) bcur[ni] = bnxt[ni];
  }

  // epilogue: per 16-row tile, transpose through LDS, then coalesced float4 stores
  const int row16 = t >> 4;   // 0..15
  const int q = t & 15;       // float4-column group base
#pragma unroll
  for (int mi = 0; mi < 4; mi++) {
    __syncthreads();  // Ls free (As dead / previous read done)
#pragma unroll
    for (int r = 0; r < 4; r++) {
#pragma unroll
      for (int ni = 0; ni < 4; ni++)
        Ls[(lg * 4 + r) * 260 + colbase + ni * 16 + l16] = acc[mi][ni][r];
    }
    __syncthreads();
    int grow = bm + mi * 16 + row16;
    if (grow < N_NODES) {
#pragma unroll
      for (int k = 0; k < 4; ++k) {
        int qc = (q + k * 16) * 4;  // float column 0..252
        float4 v = *(const float4*)&Ls[row16 * 260 + qc];
        float4 bv = *(const float4*)(bias + qc);
        v.x += bv.x; v.y += bv.y; v.z += bv.z; v.w += bv.w;
        v.x = (v.x > 0.f) ? v.x : (__expf(v.x) - 1.f);
        v.y = (v.y > 0.f) ? v.y : (__expf(v.y) - 1.f);
        v.z = (v.z > 0.f) ? v.z : (__expf(v.z) - 1.f);
        v.w = (v.w > 0.f) ? v.w : (__expf(v.w) - 1.f);
        *(float4*)(out + (size_t)grow * 256 + qc) = v;
      }
    }
  }
}

extern "C" void kernel_launch(void* const* d_in, const int* in_sizes, int n_in,
                              void* d_out, int out_size, void* d_ws, size_t ws_size,
                              hipStream_t stream) {
  const float* x = (const float*)d_in[0];
  const void* ei = d_in[1];
  const float* edge_attr = (const float*)d_in[2];
  const float* W = (const float*)d_in[3];
  const float* W_edge = (const float*)d_in[4];
  const float* att = (const float*)d_in[5];
  const float* proj_w = (const float*)d_in[6];
  const float* proj_b = (const float*)d_in[7];
  float* out = (float*)d_out;

  char* ws = (char*)d_ws;
  size_t off = 0;
  auto alloc = [&](size_t bytes) -> void* {
    void* p = (void*)(ws + off);
    off += (bytes + 255) & ~(size_t)255;
    return p;
  };
  unsigned int* xwq     = (unsigned int*)alloc((size_t)N_NODES * 256);
  float* scl4    = (float*)alloc((size_t)N_NODES * 4 * 4);
  unsigned short* outhb = (unsigned short*)alloc((size_t)N_NODES * 256 * 2);
  float* s1      = (float*)alloc((size_t)N_NODES * 4 * 4);
  float* s2      = (float*)alloc((size_t)N_NODES * 4 * 4);
  uint4* evs     = (uint4*)alloc((size_t)NBUCK * CAPS * 16);
  uint4* ovf     = (uint4*)alloc((size_t)OVF_MAX * 16);
  int* bcur      = (int*)alloc((size_t)(NBUCK + 64) * 4);
  int* ovfc      = bcur + NBUCK;
  unsigned short* Bt = (unsigned short*)alloc(65536 * 2);
  unsigned short* Pt = (unsigned short*)alloc(65536 * 2);
  float* w3      = (float*)alloc(64 * 4);
  int* flag      = (int*)alloc(256);

  const int NB_E = (E_EDGES + 4095) / 4096;  // 391

  hipMemsetAsync(bcur, 0, (size_t)(NBUCK + 64) * 4, stream);
  k_detect<<<1, 64, 0, stream>>>(ei, flag);
  k_prep<<<(131136 + 255) / 256, 256, 0, stream>>>(W, proj_w, W_edge, att, Bt, Pt, w3);
  k_gemm_x<<<(N_NODES + 63) / 64, 256, 0, stream>>>(x, Bt, att, xwq, scl4, s1, s2);
  k_edge<<<NB_E, 1024, 0, stream>>>(ei, flag, edge_attr, s1, s2, w3, bcur, evs, ovf, ovfc);
  k_aggr<<<NBUCK, 256, 0, stream>>>(bcur, evs, ovf, ovfc, xwq, scl4, outhb);
  k_gemm_out<<<(N_NODES + 63) / 64, 256, 0, stream>>>(outhb, Pt, proj_b, out);
}